// Round 6
// baseline (1127.171 us; speedup 1.0000x reference)
//
#include <hip/hip_runtime.h>
#include <hip/hip_fp16.h>

#define BN 13248
#define NE 211968
#define NBKT 8        // source buckets (src>>11); approx locality sort
#define SCAN_TOT (BN * NBKT)   // 105984
#define SCAN_NBLK 52           // 52 * 2048 = 106496 >= SCAN_TOT
#define ZSTRIDE 200   // halves per Z row (192 + 8 pad)
#define HSTRIDE 40    // halves per hb16 tau-row (32 + 8 pad)

typedef __attribute__((ext_vector_type(8))) short bf16x8;
typedef __attribute__((ext_vector_type(8))) _Float16 f16x8;
typedef __attribute__((ext_vector_type(4))) float f32x4;

__device__ __forceinline__ f32x4 mfma16b(bf16x8 a, bf16x8 b, f32x4 c) {
  return __builtin_amdgcn_mfma_f32_16x16x32_bf16(a, b, c, 0, 0, 0);
}
__device__ __forceinline__ f32x4 mfma16h(f16x8 a, f16x8 b, f32x4 c) {
  return __builtin_amdgcn_mfma_f32_16x16x32_f16(a, b, c, 0, 0, 0);
}

__device__ __forceinline__ unsigned short to_bf16(float v) {
  unsigned bits = __float_as_uint(v);
  return (unsigned short)((bits + 0x7FFFu + ((bits >> 16) & 1u)) >> 16);
}
__device__ __forceinline__ unsigned short to_f16(float v) {
  union { __half h; unsigned short s; } u; u.h = __float2half(v); return u.s;
}
__device__ __forceinline__ unsigned h2u(__half2 h) {
  union { __half2 h; unsigned u; } v; v.h = h; return v.u;
}
__device__ __forceinline__ __half2 u2h(unsigned u) {
  union { unsigned u; __half2 h; } v; v.u = u; return v.h;
}

__device__ __forceinline__ float fast_tanh(float x) {
  float e2 = __expf(2.f * x);
  return 1.f - 2.f / (e2 + 1.f);
}
__device__ __forceinline__ float fast_sig(float x) {
  return 1.f / (1.f + __expf(-x));
}

// counted vmcnt wait; sched_barrier(0) after per rule #18
template<int N>
__device__ __forceinline__ void vmwait() {
  if constexpr (N == 0)       asm volatile("s_waitcnt vmcnt(0)" ::: "memory");
  else if constexpr (N == 11) asm volatile("s_waitcnt vmcnt(11)" ::: "memory");
  else if constexpr (N == 22) asm volatile("s_waitcnt vmcnt(22)" ::: "memory");
  else if constexpr (N == 33) asm volatile("s_waitcnt vmcnt(33)" ::: "memory");
  __builtin_amdgcn_sched_barrier(0);
}
// single-wave LDS ordering fence (avoids __syncthreads' vmcnt(0) drain of the ring)
__device__ __forceinline__ void wave_lds_fence() {
  asm volatile("s_waitcnt lgkmcnt(0)" ::: "memory");
  __builtin_amdgcn_sched_barrier(0);
}

// fire-and-forget global->LDS stage of one edge's t-block (NJ*256 bytes).
template<int NJ>
__device__ __forceinline__ void stage_edge(const unsigned short* t_in, int node,
                                           char* stg, int slot, int lane) {
  const char* g = (const char*)t_in + (size_t)node * (NJ * 256);
  char* l = stg + slot * (NJ * 256);
#pragma unroll
  for (int j = 0; j < NJ; ++j)
    __builtin_amdgcn_global_load_lds(
        (const __attribute__((address_space(1))) void*)(g + j * 256 + lane * 4),
        (__attribute__((address_space(3))) void*)(l + j * 256), 4, 0, 0);
}

// stage 64 edge records (int4 each) in one width-16 instruction
__device__ __forceinline__ void stage_ce(const int4* ce, int4* celds, int g, int lane) {
  __builtin_amdgcn_global_load_lds(
      (const __attribute__((address_space(1))) void*)(ce + g * 64 + lane),
      (__attribute__((address_space(3))) void*)(celds + g * 64), 16, 0, 0);
}

// consume staged edge: each lane handles NJ dwords (u = j*64+lane) x 3 hops
template<int NJ>
__device__ __forceinline__ void consume_edge(const char* stg, int slot,
                                             const int4* celds, int i, int lane, __half2* A) {
  int4 cw = celds[i];
  __half2 w1 = u2h((unsigned)cw.y), w2 = u2h((unsigned)cw.z), w3 = u2h((unsigned)cw.w);
  const char* sp = stg + slot * (NJ * 256);
#pragma unroll
  for (int j = 0; j < NJ; ++j) {
    __half2 v = *(const __half2*)(sp + (j * 64 + lane) * 4);
    A[0 * NJ + j] = __hfma2(w1, v, A[0 * NJ + j]);
    A[1 * NJ + j] = __hfma2(w2, v, A[1 * NJ + j]);
    A[2 * NJ + j] = __hfma2(w3, v, A[2 * NJ + j]);
  }
}

// ---------------- CSR build (bucketed by source octile for L2 locality) ----------------
__global__ void k_count(const int* __restrict__ src, const int* __restrict__ dst,
                        int* __restrict__ cur_f, int* __restrict__ cur_b) {
  int e = blockIdx.x * 256 + threadIdx.x;
  if (e < NE) {
    int s = src[e], t = dst[e];
    atomicAdd(&cur_f[t * NBKT + (s >> 11)], 1);
    atomicAdd(&cur_b[s * NBKT + (t >> 11)], 1);
  }
}

// phase 1: per-block local exclusive scan (2048 entries/block) + block totals
__global__ __launch_bounds__(1024) void k_scan1(int* __restrict__ cnt_f, int* __restrict__ cnt_b,
                                                int* __restrict__ bsum) {
  __shared__ int sdata[1024];
  int b = blockIdx.x;
  int dir = (b >= SCAN_NBLK) ? 1 : 0;
  int lb = dir ? b - SCAN_NBLK : b;
  int* cnt = dir ? cnt_b : cnt_f;
  int tid = threadIdx.x;
  int i0 = lb * 2048 + tid * 2;
  int v0 = (i0 < SCAN_TOT) ? cnt[i0] : 0;
  int v1 = (i0 + 1 < SCAN_TOT) ? cnt[i0 + 1] : 0;
  int tot = v0 + v1;
  sdata[tid] = tot;
  __syncthreads();
  for (int off = 1; off < 1024; off <<= 1) {
    int add = (tid >= off) ? sdata[tid - off] : 0;
    __syncthreads();
    sdata[tid] += add;
    __syncthreads();
  }
  int excl = sdata[tid] - tot;
  if (i0 < SCAN_TOT) cnt[i0] = excl;
  if (i0 + 1 < SCAN_TOT) cnt[i0 + 1] = excl + v0;
  if (tid == 1023) bsum[b] = sdata[1023];
}

// phase 2: segmented exclusive scan of the 2*SCAN_NBLK block totals
__global__ void k_scan2(int* __restrict__ bsum) {
  __shared__ int sdata[128];
  int tid = threadIdx.x;
  int seg = (tid >= 64) ? 64 : 0;          // fwd totals in 0..51, bwd in 64..115
  int src = (tid < 64) ? tid : tid - 64 + SCAN_NBLK;
  int valid = ((tid & 63) < SCAN_NBLK);
  int v = valid ? bsum[src] : 0;
  sdata[tid] = v;
  __syncthreads();
  for (int off = 1; off < 64; off <<= 1) {
    int add = (tid - off >= seg) ? sdata[tid - off] : 0;
    __syncthreads();
    sdata[tid] += add;
    __syncthreads();
  }
  if (valid) bsum[src] = sdata[tid] - v;   // exclusive
}

// phase 3: add block offsets, emit row[] at node boundaries
__global__ __launch_bounds__(1024) void k_scan3(int* __restrict__ cnt_f, int* __restrict__ cnt_b,
                                                const int* __restrict__ bsum,
                                                int* __restrict__ row_f, int* __restrict__ row_b) {
  int b = blockIdx.x;
  int dir = (b >= SCAN_NBLK) ? 1 : 0;
  int lb = dir ? b - SCAN_NBLK : b;
  int* cnt = dir ? cnt_b : cnt_f;
  int* row = dir ? row_b : row_f;
  int off = bsum[b];
  int tid = threadIdx.x;
#pragma unroll
  for (int k = 0; k < 2; ++k) {
    int idx = lb * 2048 + tid * 2 + k;
    if (idx < SCAN_TOT) {
      int v = cnt[idx] + off;
      cnt[idx] = v;
      if ((idx & (NBKT - 1)) == 0) row[idx / NBKT] = v;
    }
  }
  if (b == 0 && tid == 0) { row_f[BN] = NE; row_b[BN] = NE; }
}

// edge record: {col, h2(w), h2(w^2), h2(w^3)}
__global__ void k_fill(const int* __restrict__ src, const int* __restrict__ dst,
                       const float* __restrict__ w,
                       int* __restrict__ cur_f, int4* __restrict__ ce_f,
                       int* __restrict__ cur_b, int4* __restrict__ ce_b) {
  int e = blockIdx.x * 256 + threadIdx.x;
  if (e < NE) {
    int s = src[e], t = dst[e];
    float wv = w[e];
    float w2 = wv * wv, w3 = w2 * wv;
    int u1 = (int)h2u(__float2half2_rn(wv));
    int u2 = (int)h2u(__float2half2_rn(w2));
    int u3 = (int)h2u(__float2half2_rn(w3));
    int p = atomicAdd(&cur_f[t * NBKT + (s >> 11)], 1); ce_f[p] = make_int4(s, u1, u2, u3);
    int q = atomicAdd(&cur_b[s * NBKT + (t >> 11)], 1); ce_b[q] = make_int4(t, u1, u2, u3);
  }
}

// ---------------- init linear ----------------
__global__ void k_init(const float* __restrict__ x, const float* __restrict__ iw,
                       const float* __restrict__ ib, float* __restrict__ h) {
  int idx = blockIdx.x * 256 + threadIdx.x;
  if (idx >= BN * 13 * 32) return;
  int c = idx & 31;
  int r = idx >> 5;          // r = tau*BN + n
  int n = r % BN;
  int tau = r / BN;
  float x0 = x[(n * 13 + tau) * 2 + 0];
  float x1 = x[(n * 13 + tau) * 2 + 1];
  h[idx] = fmaf(x0, iw[c], fmaf(x1, iw[32 + c], ib[c]));
}

// ---------------- weight pre-pack ----------------
__global__ void k_pack(const float* __restrict__ skip_w, const float* __restrict__ skip_b,
                       const float* __restrict__ w0, const float* __restrict__ w1,
                       const float* __restrict__ gcn_w,
                       const float* __restrict__ filt_w, const float* __restrict__ gate_w,
                       unsigned short* __restrict__ SWb, unsigned short* __restrict__ W0T,
                       unsigned short* __restrict__ W1T, float* __restrict__ bsum,
                       unsigned short* __restrict__ Gg16, unsigned short* __restrict__ WTC) {
  int id = blockIdx.x * 256 + threadIdx.x;
  if (id < 65536) {          // SWb[j][k=l*32+c] = skip_w[l][j][c]  (bf16, head)
    int j = id >> 8, k = id & 255;
    SWb[id] = to_bf16(skip_w[((k >> 5) * 256 + j) * 32 + (k & 31)]);
  }
  if (id < 131072) {         // W0T[jo][k] = w0[k][jo]  (bf16, head)
    int jo = id >> 8, k = id & 255;
    W0T[id] = to_bf16(w0[k * 512 + jo]);
  }
  if (id < 8192) {           // W1T[n][k] = w1[k][n], n padded to 16  (bf16, head)
    int n = id >> 9, k = id & 511;
    W1T[id] = (n < 12) ? to_bf16(w1[k * 12 + n]) : (unsigned short)0;
  }
  if (id < 256) {
    float s = 0.f;
    for (int l = 0; l < 8; ++l) s += skip_b[l * 256 + id];
    bsum[id] = s;
  }
  if (id < 49152) {          // Gg16[l][co][k=a*32+ci] = gcn_w[l][a][ci][co]  (fp16)
    int l = id / 6144, rem = id % 6144;
    int co = rem / 192, k = rem % 192;
    int a = k >> 5, ci = k & 31;
    Gg16[id] = to_f16(gcn_w[((l * 6 + a) * 32 + ci) * 32 + co]);
  }
  if (id < 32768) {          // WTC[l][g][co][k=64]: B^T for TCN MFMA (fp16)
    int l = id >> 12, rem = id & 4095;
    int g = rem >> 11, co = (rem >> 6) & 31, k = rem & 63;
    const float* srcw = (g ? gate_w : filt_w) + l * 2048;
    float v = (k < 32) ? srcw[(co * 32 + k) * 2 + 0] : srcw[(co * 32 + (k - 32)) * 2 + 1];
    WTC[id] = to_f16(v);
  }
}

// ---------------- standalone gated TCN (layer 0 only): fp16 t out ----------------
template<int LIN, int D, int TPAD>
__global__ __launch_bounds__(256) void k_tcn(const float* __restrict__ h_in, unsigned short* __restrict__ t_out,
    const float* __restrict__ fw, const float* __restrict__ fb,
    const float* __restrict__ gw, const float* __restrict__ gb) {
  constexpr int LOUT = LIN - D;
  __shared__ __align__(16) float wq[32 * 32 * 4];
  __shared__ float hl[8][LIN * 32];
  int tid = threadIdx.x;
  for (int f = tid; f < 4096; f += 256) {
    int e = f & 3, co = (f >> 2) & 31, ci = f >> 7;
    const float* srcw = (e < 2) ? fw : gw;
    wq[f] = srcw[(co * 32 + ci) * 2 + (e & 1)];
  }
  int n0 = blockIdx.x * 8;
  for (int i = tid; i < 8 * LIN * 32; i += 256) {
    int c = i & 31, r = i >> 5;
    int nl = r / LIN, tau = r % LIN;
    hl[nl][tau * 32 + c] = h_in[(tau * BN + n0 + nl) * 32 + c];
  }
  __syncthreads();
  int nl = tid >> 5, co = tid & 31;
  int n = n0 + nl;
  float accf[LOUT], accg[LOUT];
  float fbv = fb[co], gbv = gb[co];
#pragma unroll
  for (int j = 0; j < LOUT; ++j) { accf[j] = fbv; accg[j] = gbv; }
#pragma unroll
  for (int ci = 0; ci < 32; ++ci) {
    float4 wv = *(const float4*)&wq[(ci * 32 + co) * 4];
    float xr[LIN];
#pragma unroll
    for (int t = 0; t < LIN; ++t) xr[t] = hl[nl][t * 32 + ci];
#pragma unroll
    for (int j = 0; j < LOUT; ++j) {
      accf[j] = fmaf(xr[j], wv.x, accf[j]);
      accf[j] = fmaf(xr[j + D], wv.y, accf[j]);
      accg[j] = fmaf(xr[j], wv.z, accg[j]);
      accg[j] = fmaf(xr[j + D], wv.w, accg[j]);
    }
  }
#pragma unroll
  for (int j = 0; j < TPAD; ++j) {
    unsigned short v = 0;
    if (j < LOUT) v = to_f16(fast_tanh(accf[j < LOUT ? j : 0]) * fast_sig(accg[j < LOUT ? j : 0]));
    t_out[(n * TPAD + j) * 32 + co] = v;
  }
}

// ---------------- per-node output phases: Z write + agg MFMA + residual + next TCN --------
template<int LOUT, int D, int TPAD, int D2, int TPAD2, bool LAST>
__device__ __forceinline__ void do_node(__half2* acc, int n, int lane,
    unsigned short* Zl,
    const float* __restrict__ h_in, float* __restrict__ h_out,
    float* __restrict__ lastcol, unsigned short* __restrict__ t_next,
    const unsigned short* __restrict__ Wg, const float* __restrict__ bias,
    const unsigned short* __restrict__ Wtc,
    const float* __restrict__ fbn, const float* __restrict__ gbn) {
  constexpr int NJ = TPAD / 4;
  constexpr int LOUT2 = LAST ? 1 : (LOUT - D2);
  unsigned short* hb16 = Zl;             // reused after agg-MFMA A-reads
#pragma unroll
  for (int j = 0; j < NJ; ++j) {
    int u = j * 64 + lane;
    int row = u >> 4, cp = u & 15;
#pragma unroll
    for (int a3 = 0; a3 < 6; ++a3)
      *(unsigned*)(&Zl[row * ZSTRIDE + a3 * 32 + cp * 2]) = h2u(acc[a3 * NJ + j]);
  }
  wave_lds_fence();
  int m16 = lane & 15, qq = lane >> 4;
  f32x4 dacc[2];
#pragma unroll
  for (int nt = 0; nt < 2; ++nt) {
    dacc[nt] = (f32x4){0.f, 0.f, 0.f, 0.f};
#pragma unroll
    for (int ks = 0; ks < 6; ++ks) {
      f16x8 av = *(const f16x8*)(&Zl[m16 * ZSTRIDE + ks * 32 + qq * 8]);
      f16x8 bv = *(const f16x8*)((const _Float16*)Wg + (nt * 16 + m16) * 192 + ks * 32 + qq * 8);
      dacc[nt] = mfma16h(av, bv, dacc[nt]);
    }
  }
  wave_lds_fence();                      // Zl A-reads done; region becomes hb16
#pragma unroll
  for (int nt = 0; nt < 2; ++nt) {
    int co = nt * 16 + m16;
    float bco = bias[co];
#pragma unroll
    for (int r = 0; r < 4; ++r) {
      int tau = qq * 4 + r;              // C/D: col=lane&15, row=q*4+r
      if (tau < LOUT) {
        float rres = h_in[((tau + D) * BN + n) * 32 + co];
        float o = dacc[nt][r] + bco + rres;
        h_out[(tau * BN + n) * 32 + co] = o;
        if (!LAST) hb16[tau * HSTRIDE + co] = to_f16(o);
        if (tau == LOUT - 1) lastcol[n * 32 + co] = o;
      }
    }
  }
  if (!LAST) {
    wave_lds_fence();
#pragma unroll
    for (int i = 0; i < 2; ++i) {
      int co = i * 16 + m16;
      f32x4 df = (f32x4){0.f, 0.f, 0.f, 0.f};
      f32x4 dg = (f32x4){0.f, 0.f, 0.f, 0.f};
#pragma unroll
      for (int s = 0; s < 2; ++s) {
        f16x8 av = *(const f16x8*)(&hb16[(m16 + s * D2) * HSTRIDE + qq * 8]);
        f16x8 bvf = *(const f16x8*)((const _Float16*)Wtc + (0 * 32 + co) * 64 + s * 32 + qq * 8);
        f16x8 bvg = *(const f16x8*)((const _Float16*)Wtc + (1 * 32 + co) * 64 + s * 32 + qq * 8);
        df = mfma16h(av, bvf, df);
        dg = mfma16h(av, bvg, dg);
      }
      float fbv = fbn[co], gbv = gbn[co];
#pragma unroll
      for (int r = 0; r < 4; ++r) {
        int j = qq * 4 + r;
        if (j < TPAD2) {
          unsigned short v = 0;
          if (j < LOUT2)
            v = to_f16(fast_tanh(df[r] + fbv) * fast_sig(dg[r] + gbv));
          t_next[(n * TPAD2 + j) * 32 + co] = v;
        }
      }
    }
  }
}

// ---------------- fused layer: 4-node group per 64-thread block ----------
// Merged-stream gather: ce for the whole group staged once (1 drain), then a
// Q=12 global_load_lds ring flows ACROSS node/dir boundaries (stage cursor Q
// edges ahead of consume). Round-5 measurement: ~4 latency drains per 16-edge
// stream = 4400 of 5600 cyc/node. This amortizes to ~3 drains per ~128 edges.
// Node phases use a separate LDS Z region + wave-local lgkm fences so the ring
// survives them (a __syncthreads would vmcnt(0)-drain it).
template<int LOUT, int D, int TPAD, int D2, int TPAD2, bool LAST>
__global__ __launch_bounds__(64, 2) void k_fused(
    const unsigned short* __restrict__ t_in,
    const float* __restrict__ h_in, float* __restrict__ h_out,
    float* __restrict__ lastcol, unsigned short* __restrict__ t_next,
    const int* __restrict__ row_f, const int4* __restrict__ ce_f,
    const int* __restrict__ row_b, const int4* __restrict__ ce_b,
    const unsigned short* __restrict__ Wg,    // [32][192] fp16 B^T (agg)
    const float* __restrict__ bias,
    const unsigned short* __restrict__ Wtc,   // [2][32][64] fp16 B^T (next TCN)
    const float* __restrict__ fbn, const float* __restrict__ gbn) {
  constexpr int NJ = TPAD / 4;           // dwords per lane per edge block
  constexpr int Q = 12;                  // ring depth (edges in flight)
  constexpr int CAPD = 128;              // per-direction group ce capacity
  constexpr int SQB = Q * NJ * 256;      // stage ring bytes
  constexpr int CEB = CAPD * 16;
  constexpr int ZOFF = SQB + 2 * CEB + 256;
  constexpr int ZB = 16 * ZSTRIDE * 2;
  __shared__ __align__(256) char smem[ZOFF + ZB];
  char* stg = smem;
  int4* cefL = (int4*)(smem + SQB);
  int4* cebL = (int4*)(smem + SQB + CEB);
  int* lrun = (int*)(smem + SQB + 2 * CEB);    // [8][2] run bounds (local idx)
  unsigned short* Zl = (unsigned short*)(smem + ZOFF);
  int lane = threadIdx.x;
  int n0 = blockIdx.x * 4;
  int rf0 = row_f[n0], rf4 = row_f[n0 + 4];
  int rb0 = row_b[n0], rb4 = row_b[n0 + 4];
  int cf = rf4 - rf0, cb = rb4 - rb0;
  __half2 zero = __float2half2_rn(0.f);

  if (cf <= CAPD && cb <= CAPD) {
    // ---- main path: one merged pipeline over 8 runs (4 nodes x 2 dirs) ----
    for (int g = 0; g * 64 < cf; ++g) stage_ce(ce_f + rf0, cefL, g, lane);
    for (int g = 0; g * 64 < cb; ++g) stage_ce(ce_b + rb0, cebL, g, lane);
    if (lane < 8) {
      int node = lane >> 1, dir = lane & 1;
      const int* rp = dir ? row_b : row_f;
      int base = dir ? rb0 : rf0;
      lrun[lane * 2 + 0] = rp[n0 + node] - base;
      lrun[lane * 2 + 1] = rp[n0 + node + 1] - base;
    }
    wave_lds_fence();                    // lrun visible
    vmwait<0>();                         // ce tables landed (the ONE group drain)
    // stage cursor (run sr, local idx si, cached run end shi)
    int sr = 0, si = lrun[0], shi = lrun[1];
    while (sr < 8 && si >= shi) { ++sr; if (sr < 8) { si = lrun[sr * 2]; shi = lrun[sr * 2 + 1]; } }
    int sslot = 0, primed = 0;
    while (primed < Q && sr < 8) {
      int col = ((sr & 1) ? cebL : cefL)[si].x;
      stage_edge<NJ>(t_in, col, stg, sslot, lane);
      if (++sslot == Q) sslot = 0;
      ++primed; ++si;
      while (sr < 8 && si >= shi) { ++sr; if (sr < 8) { si = lrun[sr * 2]; shi = lrun[sr * 2 + 1]; } }
    }
    int cslot = 0;
    bool drained = false;
    for (int nl = 0; nl < 4; ++nl) {
      __half2 acc[6 * NJ];
#pragma unroll
      for (int i = 0; i < 6 * NJ; ++i) acc[i] = zero;
      for (int dh = 0; dh < 2; ++dh) {
        int r = nl * 2 + dh;
        int lo = lrun[r * 2], hi = lrun[r * 2 + 1];
        const int4* tab = dh ? cebL : cefL;
        __half2* A = acc + dh * 3 * NJ;
        for (int i = lo; i < hi; ++i) {
          if (sr < 8) { vmwait<(Q - 1) * NJ>(); }            // steady: inflight == Q
          else if (!drained) { vmwait<0>(); drained = true; } // tail: one drain
          consume_edge<NJ>(stg, cslot, tab, i, lane, A);
          if (++cslot == Q) cslot = 0;
          if (sr < 8) {
            int col = ((sr & 1) ? cebL : cefL)[si].x;
            stage_edge<NJ>(t_in, col, stg, sslot, lane);
            if (++sslot == Q) sslot = 0;
            ++si;
            while (sr < 8 && si >= shi) { ++sr; if (sr < 8) { si = lrun[sr * 2]; shi = lrun[sr * 2 + 1]; } }
          }
        }
      }
      do_node<LOUT, D, TPAD, D2, TPAD2, LAST>(acc, n0 + nl, lane, Zl,
          h_in, h_out, lastcol, t_next, Wg, bias, Wtc, fbn, gbn);
    }
  } else {
    // ---- fallback (degree overflow; always correct): per (node,dir) chunks ----
    for (int nl = 0; nl < 4; ++nl) {
      __half2 acc[6 * NJ];
#pragma unroll
      for (int i = 0; i < 6 * NJ; ++i) acc[i] = zero;
      for (int dh = 0; dh < 2; ++dh) {
        const int* rowp = dh ? row_b : row_f;
        const int4* cebase = dh ? ce_b : ce_f;
        __half2* A = acc + dh * 3 * NJ;
        int e0 = rowp[n0 + nl], e1 = rowp[n0 + nl + 1];
        for (int c0 = e0; c0 < e1; c0 += CAPD) {
          int cnt = min(e1 - c0, CAPD);
          for (int g = 0; g * 64 < cnt; ++g) stage_ce(cebase + c0, cefL, g, lane);
          vmwait<0>();
          int P = cnt < Q ? cnt : Q;
          int ss = 0, cs = 0;
          for (int k = 0; k < P; ++k) {
            stage_edge<NJ>(t_in, cefL[k].x, stg, ss, lane);
            if (++ss == Q) ss = 0;
          }
          int body = cnt - P;            // body>0 implies P==Q
          for (int i = 0; i < body; ++i) {
            vmwait<(Q - 1) * NJ>();
            consume_edge<NJ>(stg, cs, cefL, i, lane, A);
            stage_edge<NJ>(t_in, cefL[i + P].x, stg, ss, lane);
            if (++cs == Q) cs = 0;
            if (++ss == Q) ss = 0;
          }
          vmwait<0>();
          for (int i = body; i < cnt; ++i) {
            consume_edge<NJ>(stg, cs, cefL, i, lane, A);
            if (++cs == Q) cs = 0;
          }
        }
      }
      do_node<LOUT, D, TPAD, D2, TPAD2, LAST>(acc, n0 + nl, lane, Zl,
          h_in, h_out, lastcol, t_next, Wg, bias, Wtc, fbn, gbn);
    }
  }
}

// ------------- fused MFMA head (bf16) -------------
__device__ __forceinline__ bf16x8 ldsA(const unsigned short* buf, int stride, int row, int ks, int q) {
  int unit = ks * 4 + q;
  int addr = row * stride + ((unit ^ (row & 7)) << 3);
  return *(const bf16x8*)(buf + addr);
}

__global__ __launch_bounds__(256) void k_final(const float* __restrict__ lastcol,
    const unsigned short* __restrict__ SWb, const unsigned short* __restrict__ W0T,
    const unsigned short* __restrict__ W1T, const float* __restrict__ bsum,
    const float* __restrict__ b0, const float* __restrict__ b1,
    float* __restrict__ out) {
  __shared__ __align__(16) unsigned short Z[32 * 256];
  __shared__ __align__(16) unsigned short H[32 * 512];
  int tid = threadIdx.x;
  int wave = tid >> 6, lane = tid & 63;
  int m16 = lane & 15, q = lane >> 4;
  int n0 = blockIdx.x * 32;
#pragma unroll
  for (int it = 0; it < 32; ++it) {
    int id = it * 256 + tid;
    int m = id >> 8, k = id & 255;
    float v = lastcol[((k >> 5) * BN + n0 + m) * 32 + (k & 31)];
    Z[m * 256 + (((k >> 3) ^ (m & 7)) << 3) + (k & 7)] = to_bf16(v);
  }
  __syncthreads();
  f32x4 acc1[2][4];
#pragma unroll
  for (int mt = 0; mt < 2; ++mt)
#pragma unroll
    for (int i = 0; i < 4; ++i) acc1[mt][i] = (f32x4){0.f, 0.f, 0.f, 0.f};
#pragma unroll
  for (int ks = 0; ks < 8; ++ks) {
    bf16x8 a0 = ldsA(Z, 256, m16, ks, q);
    bf16x8 a1 = ldsA(Z, 256, 16 + m16, ks, q);
#pragma unroll
    for (int i = 0; i < 4; ++i) {
      int j = (wave * 4 + i) * 16 + m16;
      bf16x8 b = *(const bf16x8*)(SWb + j * 256 + ks * 32 + q * 8);
      acc1[0][i] = mfma16b(a0, b, acc1[0][i]);
      acc1[1][i] = mfma16b(a1, b, acc1[1][i]);
    }
  }
  __syncthreads();
#pragma unroll
  for (int i = 0; i < 4; ++i) {
    int j = (wave * 4 + i) * 16 + m16;
    float bs = bsum[j];
#pragma unroll
    for (int mt = 0; mt < 2; ++mt)
#pragma unroll
      for (int r = 0; r < 4; ++r) {
        int row = mt * 16 + q * 4 + r;
        float v = fmaxf(acc1[mt][i][r] + bs, 0.f);
        Z[row * 256 + (((j >> 3) ^ (row & 7)) << 3) + (j & 7)] = to_bf16(v);
      }
  }
  __syncthreads();
  f32x4 acc2[2][8];
#pragma unroll
  for (int mt = 0; mt < 2; ++mt)
#pragma unroll
    for (int i = 0; i < 8; ++i) acc2[mt][i] = (f32x4){0.f, 0.f, 0.f, 0.f};
#pragma unroll
  for (int ks = 0; ks < 8; ++ks) {
    bf16x8 a0 = ldsA(Z, 256, m16, ks, q);
    bf16x8 a1 = ldsA(Z, 256, 16 + m16, ks, q);
#pragma unroll
    for (int i = 0; i < 8; ++i) {
      int jo = (wave * 8 + i) * 16 + m16;
      bf16x8 b = *(const bf16x8*)(W0T + jo * 256 + ks * 32 + q * 8);
      acc2[0][i] = mfma16b(a0, b, acc2[0][i]);
      acc2[1][i] = mfma16b(a1, b, acc2[1][i]);
    }
  }
#pragma unroll
  for (int i = 0; i < 8; ++i) {
    int jo = (wave * 8 + i) * 16 + m16;
    float b0v = b0[jo];
#pragma unroll
    for (int mt = 0; mt < 2; ++mt)
#pragma unroll
      for (int r = 0; r < 4; ++r) {
        int row = mt * 16 + q * 4 + r;
        float v = fmaxf(acc2[mt][i][r] + b0v, 0.f);
        H[row * 512 + (((jo >> 3) ^ (row & 7)) << 3) + (jo & 7)] = to_bf16(v);
      }
  }
  __syncthreads();
  if (wave < 2) {
    f32x4 acc3 = (f32x4){0.f, 0.f, 0.f, 0.f};
#pragma unroll
    for (int ks = 0; ks < 16; ++ks) {
      bf16x8 a = ldsA(H, 512, wave * 16 + m16, ks, q);
      bf16x8 b = *(const bf16x8*)(W1T + m16 * 512 + ks * 32 + q * 8);
      acc3 = mfma16b(a, b, acc3);
    }
    if (m16 < 12) {
      float bv = b1[m16];
#pragma unroll
      for (int r = 0; r < 4; ++r)
        out[(n0 + wave * 16 + q * 4 + r) * 12 + m16] = acc3[r] + bv;
    }
  }
}

extern "C" void kernel_launch(void* const* d_in, const int* in_sizes, int n_in,
                              void* d_out, int out_size, void* d_ws, size_t ws_size,
                              hipStream_t stream) {
  const float* x      = (const float*)d_in[0];
  const int*   esrc   = (const int*)d_in[1];
  const int*   edst   = (const int*)d_in[2];
  const float* ew     = (const float*)d_in[3];
  const float* init_w = (const float*)d_in[4];
  const float* init_b = (const float*)d_in[5];
  const float* filt_w = (const float*)d_in[6];
  const float* filt_b = (const float*)d_in[7];
  const float* gate_w = (const float*)d_in[8];
  const float* gate_b = (const float*)d_in[9];
  const float* gcn_w  = (const float*)d_in[10];
  const float* gcn_b  = (const float*)d_in[11];
  const float* skip_w = (const float*)d_in[12];
  const float* skip_b = (const float*)d_in[13];
  const float* w0     = (const float*)d_in[14];
  const float* b0     = (const float*)d_in[15];
  const float* w1     = (const float*)d_in[16];
  const float* b1     = (const float*)d_in[17];
  float* out = (float*)d_out;

  float* base = (float*)d_ws;
  float* hA      = base;                        // 13*BN*32 f32
  float* hB      = hA + 13 * BN * 32;           // 13*BN*32 f32
  unsigned short* tA = (unsigned short*)(hB + 13 * BN * 32);  // 12*BN*32 halves
  unsigned short* tB = tA + 12 * BN * 32;                     // 12*BN*32 halves
  float* lastcol = (float*)(tB + 12 * BN * 32); // 8*BN*32 f32
  int* row_f = (int*)(lastcol + 8 * BN * 32);   // BN+2
  int* row_b = row_f + (BN + 2);                // BN+2
  int* bscan = row_b + (BN + 2);                // 2*SCAN_NBLK (+pad)
  int* cur_f = bscan + 128;                     // BN*NBKT
  int* cur_b = cur_f + BN * NBKT;               // BN*NBKT
  int4* ce_f = (int4*)(cur_b + BN * NBKT);      // NE int4 (+128 pad for 64-granular staging)
  int4* ce_b = ce_f + NE + 128;                 // NE int4 (+128 pad)
  unsigned short* SWb  = (unsigned short*)(ce_b + NE + 128);  // 65536 halves
  unsigned short* W0T  = SWb + 65536;                   // 131072 halves
  unsigned short* W1T  = W0T + 131072;                  // 8192 halves
  unsigned short* Gg16 = W1T + 8192;                    // 49152 halves
  unsigned short* WTC  = Gg16 + 49152;                  // 32768 halves
  float* bsumv = (float*)(WTC + 32768);                 // 256 f32

  hipMemsetAsync(cur_f, 0, 2 * BN * NBKT * sizeof(int), stream);
  const int egrid = (NE + 255) / 256;
  k_count<<<egrid, 256, 0, stream>>>(esrc, edst, cur_f, cur_b);
  k_scan1<<<2 * SCAN_NBLK, 1024, 0, stream>>>(cur_f, cur_b, bscan);
  k_scan2<<<1, 128, 0, stream>>>(bscan);
  k_scan3<<<2 * SCAN_NBLK, 1024, 0, stream>>>(cur_f, cur_b, bscan, row_f, row_b);
  k_fill<<<egrid, 256, 0, stream>>>(esrc, edst, ew, cur_f, ce_f, cur_b, ce_b);
  k_init<<<(BN * 13 * 32 + 255) / 256, 256, 0, stream>>>(x, init_w, init_b, hA);
  k_pack<<<512, 256, 0, stream>>>(skip_w, skip_b, w0, w1, gcn_w, filt_w, gate_w,
                                  SWb, W0T, W1T, bsumv, Gg16, WTC);

  // layer 0 TCN (standalone)
  k_tcn<13, 1, 12><<<BN / 8, 256, 0, stream>>>(hA, tA, filt_w, filt_b, gate_w, gate_b);

  // fused layers: agg(l) + TCN(l+1); 4 nodes per 64-thread block
#define FUSED(l, LOUTv, Dv, TPv, D2v, TP2v, LASTv, tin, tout, hin, hout) \
  k_fused<LOUTv, Dv, TPv, D2v, TP2v, LASTv><<<BN / 4, 64, 0, stream>>>( \
      tin, hin, hout, lastcol + l * BN * 32, tout, row_f, ce_f, row_b, ce_b, \
      Gg16 + l * 6144, gcn_b + l * 32, WTC + (l + 1) * 4096, \
      filt_b + (l + 1) * 32, gate_b + (l + 1) * 32);

  FUSED(0, 12, 1, 12, 2, 12, false, tA, tB, hA, hB)
  FUSED(1, 10, 2, 12, 1, 12, false, tB, tA, hB, hA)
  FUSED(2,  9, 1, 12, 2,  8, false, tA, tB, hA, hB)
  FUSED(3,  7, 2,  8, 1,  8, false, tB, tA, hB, hA)
  FUSED(4,  6, 1,  8, 2,  4, false, tA, tB, hA, hB)
  FUSED(5,  4, 2,  4, 1,  4, false, tB, tA, hB, hA)
  FUSED(6,  3, 1,  4, 2,  4, false, tA, tB, hA, hB)
#undef FUSED
  // last layer: agg only
  k_fused<1, 2, 4, 2, 4, true><<<BN / 4, 64, 0, stream>>>(
      tB, hB, hA, lastcol + 7 * BN * 32, tA, row_f, ce_f, row_b, ce_b,
      Gg16 + 7 * 6144, gcn_b + 7 * 32, WTC, filt_b, gate_b);

  k_final<<<BN / 32, 256, 0, stream>>>(lastcol, SWb, W0T, W1T, bsumv, b0, b1, out);
}

// Round 7
// 775.587 us; speedup vs baseline: 1.4533x; 1.4533x over previous
//
#include <hip/hip_runtime.h>
#include <hip/hip_fp16.h>

#define BN 13248
#define NE 211968
#define NBKT 8        // source buckets (src>>11); approx locality sort
#define SCAN_TOT (BN * NBKT)   // 105984
#define SCAN_NBLK 52           // 52 * 2048 = 106496 >= SCAN_TOT
#define ZSTRIDE 200   // halves per Z row (192 + 8 pad)
#define HSTRIDE 40    // halves per hb16 tau-row (32 + 8 pad)
#define HNODE 480     // 12 rows * 40

typedef __attribute__((ext_vector_type(8))) short bf16x8;
typedef __attribute__((ext_vector_type(8))) _Float16 f16x8;
typedef __attribute__((ext_vector_type(4))) float f32x4;

__device__ __forceinline__ f32x4 mfma16b(bf16x8 a, bf16x8 b, f32x4 c) {
  return __builtin_amdgcn_mfma_f32_16x16x32_bf16(a, b, c, 0, 0, 0);
}
__device__ __forceinline__ f32x4 mfma16h(f16x8 a, f16x8 b, f32x4 c) {
  return __builtin_amdgcn_mfma_f32_16x16x32_f16(a, b, c, 0, 0, 0);
}

__device__ __forceinline__ unsigned short to_bf16(float v) {
  unsigned bits = __float_as_uint(v);
  return (unsigned short)((bits + 0x7FFFu + ((bits >> 16) & 1u)) >> 16);
}
__device__ __forceinline__ unsigned short to_f16(float v) {
  union { __half h; unsigned short s; } u; u.h = __float2half(v); return u.s;
}
__device__ __forceinline__ unsigned h2u(__half2 h) {
  union { __half2 h; unsigned u; } v; v.h = h; return v.u;
}
__device__ __forceinline__ __half2 u2h(unsigned u) {
  union { unsigned u; __half2 h; } v; v.u = u; return v.h;
}

__device__ __forceinline__ float fast_tanh(float x) {
  float e2 = __expf(2.f * x);
  return 1.f - 2.f / (e2 + 1.f);
}
__device__ __forceinline__ float fast_sig(float x) {
  return 1.f / (1.f + __expf(-x));
}

// ---------------- CSR build (bucketed by source octile for L2 locality) ----------------
__global__ void k_count(const int* __restrict__ src, const int* __restrict__ dst,
                        int* __restrict__ cur_f, int* __restrict__ cur_b) {
  int e = blockIdx.x * 256 + threadIdx.x;
  if (e < NE) {
    int s = src[e], t = dst[e];
    atomicAdd(&cur_f[t * NBKT + (s >> 11)], 1);
    atomicAdd(&cur_b[s * NBKT + (t >> 11)], 1);
  }
}

// phase 1: per-block local exclusive scan (2048 entries/block) + block totals
__global__ __launch_bounds__(1024) void k_scan1(int* __restrict__ cnt_f, int* __restrict__ cnt_b,
                                                int* __restrict__ bsum) {
  __shared__ int sdata[1024];
  int b = blockIdx.x;
  int dir = (b >= SCAN_NBLK) ? 1 : 0;
  int lb = dir ? b - SCAN_NBLK : b;
  int* cnt = dir ? cnt_b : cnt_f;
  int tid = threadIdx.x;
  int i0 = lb * 2048 + tid * 2;
  int v0 = (i0 < SCAN_TOT) ? cnt[i0] : 0;
  int v1 = (i0 + 1 < SCAN_TOT) ? cnt[i0 + 1] : 0;
  int tot = v0 + v1;
  sdata[tid] = tot;
  __syncthreads();
  for (int off = 1; off < 1024; off <<= 1) {
    int add = (tid >= off) ? sdata[tid - off] : 0;
    __syncthreads();
    sdata[tid] += add;
    __syncthreads();
  }
  int excl = sdata[tid] - tot;
  if (i0 < SCAN_TOT) cnt[i0] = excl;
  if (i0 + 1 < SCAN_TOT) cnt[i0 + 1] = excl + v0;
  if (tid == 1023) bsum[b] = sdata[1023];
}

// phase 2: segmented exclusive scan of the 2*SCAN_NBLK block totals
__global__ void k_scan2(int* __restrict__ bsum) {
  __shared__ int sdata[128];
  int tid = threadIdx.x;
  int seg = (tid >= 64) ? 64 : 0;          // fwd totals in 0..51, bwd in 64..115
  int src = (tid < 64) ? tid : tid - 64 + SCAN_NBLK;
  int valid = ((tid & 63) < SCAN_NBLK);
  int v = valid ? bsum[src] : 0;
  sdata[tid] = v;
  __syncthreads();
  for (int off = 1; off < 64; off <<= 1) {
    int add = (tid - off >= seg) ? sdata[tid - off] : 0;
    __syncthreads();
    sdata[tid] += add;
    __syncthreads();
  }
  if (valid) bsum[src] = sdata[tid] - v;   // exclusive
}

// phase 3: add block offsets, emit row[] at node boundaries
__global__ __launch_bounds__(1024) void k_scan3(int* __restrict__ cnt_f, int* __restrict__ cnt_b,
                                                const int* __restrict__ bsum,
                                                int* __restrict__ row_f, int* __restrict__ row_b) {
  int b = blockIdx.x;
  int dir = (b >= SCAN_NBLK) ? 1 : 0;
  int lb = dir ? b - SCAN_NBLK : b;
  int* cnt = dir ? cnt_b : cnt_f;
  int* row = dir ? row_b : row_f;
  int off = bsum[b];
  int tid = threadIdx.x;
#pragma unroll
  for (int k = 0; k < 2; ++k) {
    int idx = lb * 2048 + tid * 2 + k;
    if (idx < SCAN_TOT) {
      int v = cnt[idx] + off;
      cnt[idx] = v;
      if ((idx & (NBKT - 1)) == 0) row[idx / NBKT] = v;
    }
  }
  if (b == 0 && tid == 0) { row_f[BN] = NE; row_b[BN] = NE; }
}

// edge record: {col, h2(w), h2(w^2), h2(w^3)}
// After this kernel, cur_f[n*NBKT+o] / cur_b[n*NBKT+o] hold the END offset of
// bucket (n, o) — preserved and reused by k_fused's octile-phased edge loop.
__global__ void k_fill(const int* __restrict__ src, const int* __restrict__ dst,
                       const float* __restrict__ w,
                       int* __restrict__ cur_f, int4* __restrict__ ce_f,
                       int* __restrict__ cur_b, int4* __restrict__ ce_b) {
  int e = blockIdx.x * 256 + threadIdx.x;
  if (e < NE) {
    int s = src[e], t = dst[e];
    float wv = w[e];
    float w2 = wv * wv, w3 = w2 * wv;
    int u1 = (int)h2u(__float2half2_rn(wv));
    int u2 = (int)h2u(__float2half2_rn(w2));
    int u3 = (int)h2u(__float2half2_rn(w3));
    int p = atomicAdd(&cur_f[t * NBKT + (s >> 11)], 1); ce_f[p] = make_int4(s, u1, u2, u3);
    int q = atomicAdd(&cur_b[s * NBKT + (t >> 11)], 1); ce_b[q] = make_int4(t, u1, u2, u3);
  }
}

// ---------------- init linear ----------------
__global__ void k_init(const float* __restrict__ x, const float* __restrict__ iw,
                       const float* __restrict__ ib, float* __restrict__ h) {
  int idx = blockIdx.x * 256 + threadIdx.x;
  if (idx >= BN * 13 * 32) return;
  int c = idx & 31;
  int r = idx >> 5;          // r = tau*BN + n
  int n = r % BN;
  int tau = r / BN;
  float x0 = x[(n * 13 + tau) * 2 + 0];
  float x1 = x[(n * 13 + tau) * 2 + 1];
  h[idx] = fmaf(x0, iw[c], fmaf(x1, iw[32 + c], ib[c]));
}

// ---------------- weight pre-pack ----------------
__global__ void k_pack(const float* __restrict__ skip_w, const float* __restrict__ skip_b,
                       const float* __restrict__ w0, const float* __restrict__ w1,
                       const float* __restrict__ gcn_w,
                       const float* __restrict__ filt_w, const float* __restrict__ gate_w,
                       unsigned short* __restrict__ SWb, unsigned short* __restrict__ W0T,
                       unsigned short* __restrict__ W1T, float* __restrict__ bsum,
                       unsigned short* __restrict__ Gg16, unsigned short* __restrict__ WTC) {
  int id = blockIdx.x * 256 + threadIdx.x;
  if (id < 65536) {          // SWb[j][k=l*32+c] = skip_w[l][j][c]  (bf16, head)
    int j = id >> 8, k = id & 255;
    SWb[id] = to_bf16(skip_w[((k >> 5) * 256 + j) * 32 + (k & 31)]);
  }
  if (id < 131072) {         // W0T[jo][k] = w0[k][jo]  (bf16, head)
    int jo = id >> 8, k = id & 255;
    W0T[id] = to_bf16(w0[k * 512 + jo]);
  }
  if (id < 8192) {           // W1T[n][k] = w1[k][n], n padded to 16  (bf16, head)
    int n = id >> 9, k = id & 511;
    W1T[id] = (n < 12) ? to_bf16(w1[k * 12 + n]) : (unsigned short)0;
  }
  if (id < 256) {
    float s = 0.f;
    for (int l = 0; l < 8; ++l) s += skip_b[l * 256 + id];
    bsum[id] = s;
  }
  if (id < 49152) {          // Gg16[l][co][k=a*32+ci] = gcn_w[l][a][ci][co]  (fp16)
    int l = id / 6144, rem = id % 6144;
    int co = rem / 192, k = rem % 192;
    int a = k >> 5, ci = k & 31;
    Gg16[id] = to_f16(gcn_w[((l * 6 + a) * 32 + ci) * 32 + co]);
  }
  if (id < 32768) {          // WTC[l][g][co][k=64]: B^T for TCN MFMA (fp16)
    int l = id >> 12, rem = id & 4095;
    int g = rem >> 11, co = (rem >> 6) & 31, k = rem & 63;
    const float* srcw = (g ? gate_w : filt_w) + l * 2048;
    float v = (k < 32) ? srcw[(co * 32 + k) * 2 + 0] : srcw[(co * 32 + (k - 32)) * 2 + 1];
    WTC[id] = to_f16(v);
  }
}

// ---------------- standalone gated TCN (layer 0 only): fp16 t out ----------------
template<int LIN, int D, int TPAD>
__global__ __launch_bounds__(256) void k_tcn(const float* __restrict__ h_in, unsigned short* __restrict__ t_out,
    const float* __restrict__ fw, const float* __restrict__ fb,
    const float* __restrict__ gw, const float* __restrict__ gb) {
  constexpr int LOUT = LIN - D;
  __shared__ __align__(16) float wq[32 * 32 * 4];
  __shared__ float hl[8][LIN * 32];
  int tid = threadIdx.x;
  for (int f = tid; f < 4096; f += 256) {
    int e = f & 3, co = (f >> 2) & 31, ci = f >> 7;
    const float* srcw = (e < 2) ? fw : gw;
    wq[f] = srcw[(co * 32 + ci) * 2 + (e & 1)];
  }
  int n0 = blockIdx.x * 8;
  for (int i = tid; i < 8 * LIN * 32; i += 256) {
    int c = i & 31, r = i >> 5;
    int nl = r / LIN, tau = r % LIN;
    hl[nl][tau * 32 + c] = h_in[(tau * BN + n0 + nl) * 32 + c];
  }
  __syncthreads();
  int nl = tid >> 5, co = tid & 31;
  int n = n0 + nl;
  float accf[LOUT], accg[LOUT];
  float fbv = fb[co], gbv = gb[co];
#pragma unroll
  for (int j = 0; j < LOUT; ++j) { accf[j] = fbv; accg[j] = gbv; }
#pragma unroll
  for (int ci = 0; ci < 32; ++ci) {
    float4 wv = *(const float4*)&wq[(ci * 32 + co) * 4];
    float xr[LIN];
#pragma unroll
    for (int t = 0; t < LIN; ++t) xr[t] = hl[nl][t * 32 + ci];
#pragma unroll
    for (int j = 0; j < LOUT; ++j) {
      accf[j] = fmaf(xr[j], wv.x, accf[j]);
      accf[j] = fmaf(xr[j + D], wv.y, accf[j]);
      accg[j] = fmaf(xr[j], wv.z, accg[j]);
      accg[j] = fmaf(xr[j + D], wv.w, accg[j]);
    }
  }
#pragma unroll
  for (int j = 0; j < TPAD; ++j) {
    unsigned short v = 0;
    if (j < LOUT) v = to_f16(fast_tanh(accf[j < LOUT ? j : 0]) * fast_sig(accg[j < LOUT ? j : 0]));
    t_out[(n * TPAD + j) * 32 + co] = v;
  }
}

// ---------------- gather: skip loads of known-zero padded rows ----------------
template<int TPAD, int NT>
__device__ __forceinline__ void edge_fma(const int4& c, const uint2 (&u)[NT], __half2* A) {
  __half2 wh0 = u2h((unsigned)c.y), wh1 = u2h((unsigned)c.z), wh2 = u2h((unsigned)c.w);
#pragma unroll
  for (int j = 0; j < NT; ++j) {
    __half2 v0 = u2h(u[j].x), v1 = u2h(u[j].y);
    A[(0 * NT + j) * 2 + 0] = __hfma2(wh0, v0, A[(0 * NT + j) * 2 + 0]);
    A[(0 * NT + j) * 2 + 1] = __hfma2(wh0, v1, A[(0 * NT + j) * 2 + 1]);
    A[(1 * NT + j) * 2 + 0] = __hfma2(wh1, v0, A[(1 * NT + j) * 2 + 0]);
    A[(1 * NT + j) * 2 + 1] = __hfma2(wh1, v1, A[(1 * NT + j) * 2 + 1]);
    A[(2 * NT + j) * 2 + 0] = __hfma2(wh2, v0, A[(2 * NT + j) * 2 + 0]);
    A[(2 * NT + j) * 2 + 1] = __hfma2(wh2, v1, A[(2 * NT + j) * 2 + 1]);
  }
}

template<int TPAD, int NT, int LOUTT>
__device__ __forceinline__ void gather_dir(const unsigned short* __restrict__ t_in,
    int e0, int e1, const int4* __restrict__ ce, int rowoff0, int rowbase, __half2* A) {
  constexpr bool FULL = (LOUTT >= TPAD);
  constexpr int EB = 4;
  int e = e0;
  for (; e + EB <= e1; e += EB) {
    int4 c[EB];
    uint2 u[EB][NT];
#pragma unroll
    for (int k = 0; k < EB; ++k) c[k] = ce[e + k];
#pragma unroll
    for (int k = 0; k < EB; ++k) {
      const unsigned short* p = t_in + c[k].x * (TPAD * 32) + rowoff0;
#pragma unroll
      for (int j = 0; j < NT; ++j) {
        if (FULL || rowbase + j < LOUTT) u[k][j] = *(const uint2*)(p + j * 32);
        else u[k][j] = make_uint2(0u, 0u);
      }
    }
#pragma unroll
    for (int k = 0; k < EB; ++k) edge_fma<TPAD, NT>(c[k], u[k], A);
  }
  for (; e < e1; ++e) {
    int4 c = ce[e];
    uint2 u[NT];
    const unsigned short* p = t_in + c.x * (TPAD * 32) + rowoff0;
#pragma unroll
    for (int j = 0; j < NT; ++j) {
      if (FULL || rowbase + j < LOUTT) u[j] = *(const uint2*)(p + j * 32);
      else u[j] = make_uint2(0u, 0u);
    }
    edge_fma<TPAD, NT>(c, u, A);
  }
}

// ---------------- fused layer: agg (MFMA f16) + residual + next-layer TCN (MFMA f16) --------
// Round-0 structure (proven best) + OCTILE-PHASED edge loop: all blocks walk
// source octiles in the same order, so the instantaneous gather working set is
// ~1-3 octiles (1.5-4.5 MB) instead of all of t_in (10 MB) -> L2-resident
// instead of Infinity-Cache-resident. Accumulation order is UNCHANGED (CSR rows
// were already bucket-sorted); only timing changes. Tests the measured ~4.2 TB/s
// cross-structure gather ceiling (rounds 0/3/4/5 all converge there).
template<int LOUT, int D, int TPAD, int D2, int TPAD2, bool LAST>
__global__ __launch_bounds__(128, 4) void k_fused(
    const unsigned short* __restrict__ t_in,
    const float* __restrict__ h_in, float* __restrict__ h_out,
    float* __restrict__ lastcol, unsigned short* __restrict__ t_next,
    const int* __restrict__ row_f, const int4* __restrict__ ce_f,
    const int* __restrict__ row_b, const int4* __restrict__ ce_b,
    const int* __restrict__ bkt_f, const int* __restrict__ bkt_b,  // bucket END offsets
    const unsigned short* __restrict__ Wg,    // [32][192] fp16 B^T (agg)
    const float* __restrict__ bias,
    const unsigned short* __restrict__ Wtc,   // [2][32][64] fp16 B^T (next TCN)
    const float* __restrict__ fbn, const float* __restrict__ gbn) {
  constexpr int NT = TPAD / 4;
  constexpr int LOUT2 = LAST ? 1 : (LOUT - D2);
  constexpr int SBYTES = 4 * TPAD * ZSTRIDE * 2;
  __shared__ __align__(16) char smem[SBYTES];
  unsigned short* Zl = (unsigned short*)smem;
  unsigned short* hb16 = (unsigned short*)smem;    // reused after agg-MFMA
  int tid = threadIdx.x;
  int nl = tid >> 5, lane32 = tid & 31;
  int tl = lane32 >> 3;
  int c4 = (lane32 & 7) << 2;
  int n0 = blockIdx.x * 4;
  int n = n0 + nl;
  int rowbase = tl * NT;
  int rowoff0 = rowbase * 32 + c4;
  __half2 acc[6 * NT * 2];
  __half2 zero = __float2half2_rn(0.f);
#pragma unroll
  for (int i = 0; i < 6 * NT * 2; ++i) acc[i] = zero;
  // octile-phased gather: same edges, same order, bucket-granular outer loop
  {
    int ef = row_f[n], eb = row_b[n];
    for (int o = 0; o < NBKT; ++o) {
      int ef1 = bkt_f[n * NBKT + o];
      int eb1 = bkt_b[n * NBKT + o];
      gather_dir<TPAD, NT, LOUT>(t_in, ef, ef1, ce_f, rowoff0, rowbase, acc);
      gather_dir<TPAD, NT, LOUT>(t_in, eb, eb1, ce_b, rowoff0, rowbase, acc + 3 * NT * 2);
      ef = ef1; eb = eb1;
    }
  }
#pragma unroll
  for (int j = 0; j < NT; ++j) {
    int m = nl * TPAD + rowbase + j;
#pragma unroll
    for (int a = 0; a < 6; ++a) {
      uint2 v = make_uint2(h2u(acc[(a * NT + j) * 2 + 0]), h2u(acc[(a * NT + j) * 2 + 1]));
      *(uint2*)(&Zl[m * ZSTRIDE + a * 32 + c4]) = v;
    }
  }
  __syncthreads();
  // agg MFMA: D[4*TPAD rows][32 co] = Z[4*TPAD][192] @ Wg[192][32]
  int wave = tid >> 6, lane = tid & 63;
  int m16 = lane & 15, q = lane >> 4;
  f32x4 dacc[NT];
#pragma unroll
  for (int i = 0; i < NT; ++i) {
    int u = wave * NT + i;
    int mt = u >> 1, nt = u & 1;
    dacc[i] = (f32x4){0.f, 0.f, 0.f, 0.f};
#pragma unroll
    for (int ks = 0; ks < 6; ++ks) {
      f16x8 av = *(const f16x8*)(&Zl[(mt * 16 + m16) * ZSTRIDE + ks * 32 + q * 8]);
      f16x8 bv = *(const f16x8*)((const _Float16*)Wg + (nt * 16 + m16) * 192 + ks * 32 + q * 8);
      dacc[i] = mfma16h(av, bv, dacc[i]);
    }
  }
  __syncthreads();   // Zl dead; smem becomes hb16
#pragma unroll
  for (int i = 0; i < NT; ++i) {
    int u = wave * NT + i;
    int mt = u >> 1, nt = u & 1;
    int co = nt * 16 + m16;
    float bco = bias[co];
#pragma unroll
    for (int r = 0; r < 4; ++r) {
      int mm = mt * 16 + q * 4 + r;           // C/D: col=lane&15, row=q*4+r
      int node = mm / TPAD;
      int tau = mm % TPAD;
      if (tau < LOUT) {
        float rres = h_in[((tau + D) * BN + n0 + node) * 32 + co];
        float o = dacc[i][r] + bco + rres;
        h_out[(tau * BN + n0 + node) * 32 + co] = o;
        if (!LAST) hb16[node * HNODE + tau * HSTRIDE + co] = to_f16(o);
        if (tau == LOUT - 1) lastcol[(n0 + node) * 32 + co] = o;
      }
    }
  }
  if (!LAST) {
    __syncthreads();
    // TCN via MFMA: A row m16 = j (conv out step), K=64: [h[j][ci], h[j+D2][ci]]
#pragma unroll
    for (int i = 0; i < 4; ++i) {
      int u = wave * 4 + i;
      int node = u >> 1, ntc = u & 1;
      int co = ntc * 16 + m16;
      f32x4 df = (f32x4){0.f, 0.f, 0.f, 0.f};
      f32x4 dg = (f32x4){0.f, 0.f, 0.f, 0.f};
#pragma unroll
      for (int s = 0; s < 2; ++s) {
        f16x8 av = *(const f16x8*)(&hb16[node * HNODE + (m16 + s * D2) * HSTRIDE + q * 8]);
        f16x8 bvf = *(const f16x8*)((const _Float16*)Wtc + (0 * 32 + co) * 64 + s * 32 + q * 8);
        f16x8 bvg = *(const f16x8*)((const _Float16*)Wtc + (1 * 32 + co) * 64 + s * 32 + q * 8);
        df = mfma16h(av, bvf, df);
        dg = mfma16h(av, bvg, dg);
      }
      float fbv = fbn[co], gbv = gbn[co];
#pragma unroll
      for (int r = 0; r < 4; ++r) {
        int j = q * 4 + r;
        if (j < TPAD2) {
          unsigned short v = 0;
          if (j < LOUT2)
            v = to_f16(fast_tanh(df[r] + fbv) * fast_sig(dg[r] + gbv));
          t_next[((n0 + node) * TPAD2 + j) * 32 + co] = v;
        }
      }
    }
  }
}

// ------------- fused MFMA head (bf16) -------------
__device__ __forceinline__ bf16x8 ldsA(const unsigned short* buf, int stride, int row, int ks, int q) {
  int unit = ks * 4 + q;
  int addr = row * stride + ((unit ^ (row & 7)) << 3);
  return *(const bf16x8*)(buf + addr);
}

__global__ __launch_bounds__(256) void k_final(const float* __restrict__ lastcol,
    const unsigned short* __restrict__ SWb, const unsigned short* __restrict__ W0T,
    const unsigned short* __restrict__ W1T, const float* __restrict__ bsum,
    const float* __restrict__ b0, const float* __restrict__ b1,
    float* __restrict__ out) {
  __shared__ __align__(16) unsigned short Z[32 * 256];
  __shared__ __align__(16) unsigned short H[32 * 512];
  int tid = threadIdx.x;
  int wave = tid >> 6, lane = tid & 63;
  int m16 = lane & 15, q = lane >> 4;
  int n0 = blockIdx.x * 32;
#pragma unroll
  for (int it = 0; it < 32; ++it) {
    int id = it * 256 + tid;
    int m = id >> 8, k = id & 255;
    float v = lastcol[((k >> 5) * BN + n0 + m) * 32 + (k & 31)];
    Z[m * 256 + (((k >> 3) ^ (m & 7)) << 3) + (k & 7)] = to_bf16(v);
  }
  __syncthreads();
  f32x4 acc1[2][4];
#pragma unroll
  for (int mt = 0; mt < 2; ++mt)
#pragma unroll
    for (int i = 0; i < 4; ++i) acc1[mt][i] = (f32x4){0.f, 0.f, 0.f, 0.f};
#pragma unroll
  for (int ks = 0; ks < 8; ++ks) {
    bf16x8 a0 = ldsA(Z, 256, m16, ks, q);
    bf16x8 a1 = ldsA(Z, 256, 16 + m16, ks, q);
#pragma unroll
    for (int i = 0; i < 4; ++i) {
      int j = (wave * 4 + i) * 16 + m16;
      bf16x8 b = *(const bf16x8*)(SWb + j * 256 + ks * 32 + q * 8);
      acc1[0][i] = mfma16b(a0, b, acc1[0][i]);
      acc1[1][i] = mfma16b(a1, b, acc1[1][i]);
    }
  }
  __syncthreads();
#pragma unroll
  for (int i = 0; i < 4; ++i) {
    int j = (wave * 4 + i) * 16 + m16;
    float bs = bsum[j];
#pragma unroll
    for (int mt = 0; mt < 2; ++mt)
#pragma unroll
      for (int r = 0; r < 4; ++r) {
        int row = mt * 16 + q * 4 + r;
        float v = fmaxf(acc1[mt][i][r] + bs, 0.f);
        Z[row * 256 + (((j >> 3) ^ (row & 7)) << 3) + (j & 7)] = to_bf16(v);
      }
  }
  __syncthreads();
  f32x4 acc2[2][8];
#pragma unroll
  for (int mt = 0; mt < 2; ++mt)
#pragma unroll
    for (int i = 0; i < 8; ++i) acc2[mt][i] = (f32x4){0.f, 0.f, 0.f, 0.f};
#pragma unroll
  for (int ks = 0; ks < 8; ++ks) {
    bf16x8 a0 = ldsA(Z, 256, m16, ks, q);
    bf16x8 a1 = ldsA(Z, 256, 16 + m16, ks, q);
#pragma unroll
    for (int i = 0; i < 8; ++i) {
      int jo = (wave * 8 + i) * 16 + m16;
      bf16x8 b = *(const bf16x8*)(W0T + jo * 256 + ks * 32 + q * 8);
      acc2[0][i] = mfma16b(a0, b, acc2[0][i]);
      acc2[1][i] = mfma16b(a1, b, acc2[1][i]);
    }
  }
#pragma unroll
  for (int i = 0; i < 8; ++i) {
    int jo = (wave * 8 + i) * 16 + m16;
    float b0v = b0[jo];
#pragma unroll
    for (int mt = 0; mt < 2; ++mt)
#pragma unroll
      for (int r = 0; r < 4; ++r) {
        int row = mt * 16 + q * 4 + r;
        float v = fmaxf(acc2[mt][i][r] + b0v, 0.f);
        H[row * 512 + (((jo >> 3) ^ (row & 7)) << 3) + (jo & 7)] = to_bf16(v);
      }
  }
  __syncthreads();
  if (wave < 2) {
    f32x4 acc3 = (f32x4){0.f, 0.f, 0.f, 0.f};
#pragma unroll
    for (int ks = 0; ks < 16; ++ks) {
      bf16x8 a = ldsA(H, 512, wave * 16 + m16, ks, q);
      bf16x8 b = *(const bf16x8*)(W1T + m16 * 512 + ks * 32 + q * 8);
      acc3 = mfma16b(a, b, acc3);
    }
    if (m16 < 12) {
      float bv = b1[m16];
#pragma unroll
      for (int r = 0; r < 4; ++r)
        out[(n0 + wave * 16 + q * 4 + r) * 12 + m16] = acc3[r] + bv;
    }
  }
}

extern "C" void kernel_launch(void* const* d_in, const int* in_sizes, int n_in,
                              void* d_out, int out_size, void* d_ws, size_t ws_size,
                              hipStream_t stream) {
  const float* x      = (const float*)d_in[0];
  const int*   esrc   = (const int*)d_in[1];
  const int*   edst   = (const int*)d_in[2];
  const float* ew     = (const float*)d_in[3];
  const float* init_w = (const float*)d_in[4];
  const float* init_b = (const float*)d_in[5];
  const float* filt_w = (const float*)d_in[6];
  const float* filt_b = (const float*)d_in[7];
  const float* gate_w = (const float*)d_in[8];
  const float* gate_b = (const float*)d_in[9];
  const float* gcn_w  = (const float*)d_in[10];
  const float* gcn_b  = (const float*)d_in[11];
  const float* skip_w = (const float*)d_in[12];
  const float* skip_b = (const float*)d_in[13];
  const float* w0     = (const float*)d_in[14];
  const float* b0     = (const float*)d_in[15];
  const float* w1     = (const float*)d_in[16];
  const float* b1     = (const float*)d_in[17];
  float* out = (float*)d_out;

  float* base = (float*)d_ws;
  float* hA      = base;                        // 13*BN*32 f32
  float* hB      = hA + 13 * BN * 32;           // 13*BN*32 f32
  unsigned short* tA = (unsigned short*)(hB + 13 * BN * 32);  // 12*BN*32 halves
  unsigned short* tB = tA + 12 * BN * 32;                     // 12*BN*32 halves
  float* lastcol = (float*)(tB + 12 * BN * 32); // 8*BN*32 f32
  int* row_f = (int*)(lastcol + 8 * BN * 32);   // BN+2
  int* row_b = row_f + (BN + 2);                // BN+2
  int* bscan = row_b + (BN + 2);                // 2*SCAN_NBLK (+pad)
  int* cur_f = bscan + 128;                     // BN*NBKT
  int* cur_b = cur_f + BN * NBKT;               // BN*NBKT
  int4* ce_f = (int4*)(cur_b + BN * NBKT);      // NE int4
  int4* ce_b = ce_f + NE;                       // NE int4
  unsigned short* SWb  = (unsigned short*)(ce_b + NE);  // 65536 halves
  unsigned short* W0T  = SWb + 65536;                   // 131072 halves
  unsigned short* W1T  = W0T + 131072;                  // 8192 halves
  unsigned short* Gg16 = W1T + 8192;                    // 49152 halves
  unsigned short* WTC  = Gg16 + 49152;                  // 32768 halves
  float* bsumv = (float*)(WTC + 32768);                 // 256 f32

  hipMemsetAsync(cur_f, 0, 2 * BN * NBKT * sizeof(int), stream);
  const int egrid = (NE + 255) / 256;
  k_count<<<egrid, 256, 0, stream>>>(esrc, edst, cur_f, cur_b);
  k_scan1<<<2 * SCAN_NBLK, 1024, 0, stream>>>(cur_f, cur_b, bscan);
  k_scan2<<<1, 128, 0, stream>>>(bscan);
  k_scan3<<<2 * SCAN_NBLK, 1024, 0, stream>>>(cur_f, cur_b, bscan, row_f, row_b);
  k_fill<<<egrid, 256, 0, stream>>>(esrc, edst, ew, cur_f, ce_f, cur_b, ce_b);
  k_init<<<(BN * 13 * 32 + 255) / 256, 256, 0, stream>>>(x, init_w, init_b, hA);
  k_pack<<<512, 256, 0, stream>>>(skip_w, skip_b, w0, w1, gcn_w, filt_w, gate_w,
                                  SWb, W0T, W1T, bsumv, Gg16, WTC);

  // layer 0 TCN (standalone)
  k_tcn<13, 1, 12><<<BN / 8, 256, 0, stream>>>(hA, tA, filt_w, filt_b, gate_w, gate_b);

  // fused layers: agg(l) + TCN(l+1)
#define FUSED(l, LOUTv, Dv, TPv, D2v, TP2v, LASTv, tin, tout, hin, hout) \
  k_fused<LOUTv, Dv, TPv, D2v, TP2v, LASTv><<<BN / 4, 128, 0, stream>>>( \
      tin, hin, hout, lastcol + l * BN * 32, tout, row_f, ce_f, row_b, ce_b, \
      cur_f, cur_b, \
      Gg16 + l * 6144, gcn_b + l * 32, WTC + (l + 1) * 4096, \
      filt_b + (l + 1) * 32, gate_b + (l + 1) * 32);

  FUSED(0, 12, 1, 12, 2, 12, false, tA, tB, hA, hB)
  FUSED(1, 10, 2, 12, 1, 12, false, tB, tA, hB, hA)
  FUSED(2,  9, 1, 12, 2,  8, false, tA, tB, hA, hB)
  FUSED(3,  7, 2,  8, 1,  8, false, tB, tA, hB, hA)
  FUSED(4,  6, 1,  8, 2,  4, false, tA, tB, hA, hB)
  FUSED(5,  4, 2,  4, 1,  4, false, tB, tA, hB, hA)
  FUSED(6,  3, 1,  4, 2,  4, false, tA, tB, hA, hB)
#undef FUSED
  // last layer: agg only
  k_fused<1, 2, 4, 2, 4, true><<<BN / 4, 128, 0, stream>>>(
      tB, hB, hA, lastcol + 7 * BN * 32, tA, row_f, ce_f, row_b, ce_b,
      cur_f, cur_b,
      Gg16 + 7 * 6144, gcn_b + 7 * 32, WTC, filt_b, gate_b);

  k_final<<<BN / 32, 256, 0, stream>>>(lastcol, SWb, W0T, W1T, bsumv, b0, b1, out);
}